// Round 8
// baseline (2006.722 us; speedup 1.0000x reference)
//
#include <hip/hip_runtime.h>

#define DEVINL __device__ __forceinline__

constexpr int NT   = 32768;   // 64*512 nodes
constexpr int DH   = 128;
constexpr int NE   = 262144;
constexpr int BGR  = 64;
constexpr int NPG  = 512;
constexpr int LAYS = 5;
constexpr size_t LSTR = 32768*3 + 98304;   // per-layer packed: we1a, we1b, we2, wh

typedef __attribute__((ext_vector_type(8))) short bf16x8;
typedef __attribute__((ext_vector_type(4))) float f32x4;
typedef __attribute__((ext_vector_type(4))) unsigned int uint4v;
typedef unsigned int uint;

DEVINL float siluf(float v){ return v * (1.0f/(1.0f + __expf(-v))); }
DEVINL float tanh_fast(float x){ float e = __expf(2.0f*x); return 1.0f - 2.0f/(e + 1.0f); }

DEVINL uint bf16_rne(float f){
  uint x = __float_as_uint(f);
  return (x + 0x7fffu + ((x>>16)&1u)) >> 16;
}

// split one f32 into hi (truncated bf16) + lo (rne bf16 of residual): ~16-bit mantissa total
DEVINL void split8(const float* m, bf16x8& h, bf16x8& l){
  #pragma unroll
  for (int j=0;j<8;j++){
    uint x  = __float_as_uint(m[j]);
    uint hb = x >> 16;
    float hf = __uint_as_float(hb<<16);
    uint lb = bf16_rne(m[j] - hf);
    h[j] = (short)hb; l[j] = (short)lb;
  }
}

// 3-term split-bf16 MFMA accumulate: acc += A*B with ~f32 precision (drops al*bl)
DEVINL f32x4 mma3(bf16x8 ah, bf16x8 al, bf16x8 bh, bf16x8 bl, f32x4 acc){
  acc = __builtin_amdgcn_mfma_f32_16x16x32_bf16(al, bh, acc, 0,0,0);
  acc = __builtin_amdgcn_mfma_f32_16x16x32_bf16(ah, bl, acc, 0,0,0);
  acc = __builtin_amdgcn_mfma_f32_16x16x32_bf16(ah, bh, acc, 0,0,0);
  return acc;
}

#define GLOAD_LDS16(g, l) __builtin_amdgcn_global_load_lds( \
    (const __attribute__((address_space(1))) void*)(g), \
    (__attribute__((address_space(3))) void*)(l), 16, 0, 0)

// ---------------- fused weight prep: all 16 weight matrices in ONE launch ----------------
// Packs f32 [k][col] (or transposed) -> split bf16 planes in MFMA B-fragment order:
// per 32-k chunk (8192 shorts): hi at [q*1024 + col*8 + j], lo at +4096; kc = k>>5.
__global__ __launch_bounds__(256) void k_prep_all(
    const float* __restrict__ W_emb, const float* __restrict__ We1,
    const float* __restrict__ We2,  const float* __restrict__ Wh,
    short* __restrict__ wemb_p, short* __restrict__ lay_p)
{
  const int idx = blockIdx.x*256 + threadIdx.x;
  const float* src; short* dst; int v; bool trans = false;
  if (idx < 16384){ src = W_emb; dst = wemb_p; v = idx; trans = true; }
  else {
    const int u = idx - 16384;
    const int layer = u / 98304;
    const int w = u - layer*98304;
    short* p = lay_p + (size_t)layer*LSTR;
    if (w < 16384)      { src = We1 + (size_t)layer*257*DH;          dst = p;         v = w; }
    else if (w < 32768) { src = We1 + (size_t)layer*257*DH + 128*DH; dst = p + 32768; v = w - 16384; }
    else if (w < 49152) { src = We2 + (size_t)layer*DH*DH;           dst = p + 65536; v = w - 32768; }
    else                { src = Wh  + (size_t)layer*3*DH*DH;         dst = p + 98304; v = w - 49152; }
  }
  const int k = v>>7, col = v&127;
  const float val = trans ? src[(size_t)col*128 + k] : src[(size_t)k*128 + col];
  uint hb = __float_as_uint(val) >> 16;
  float hf = __uint_as_float(hb<<16);
  uint lb = bf16_rne(val - hf);
  const int kc = k>>5, q = (k&31)>>3, j = k&7;
  const size_t o = (size_t)kc*8192 + q*1024 + col*8 + j;
  dst[o]        = (short)hb;
  dst[o + 4096] = (short)lb;
}

// ---------------- sort / degree (both edge sets per launch) ----------------
__global__ __launch_bounds__(256) void k_hist2(const int* __restrict__ edst,
                                               const int* __restrict__ cdst,
                                               int* __restrict__ cnt){
  const int half = blockIdx.x >= (NE/256);
  const int e = (blockIdx.x - half*(NE/256))*256 + threadIdx.x;
  const int* d = half ? cdst : edst;
  atomicAdd(&cnt[half*NT + d[e]], 1);
}

// grid = 2 blocks; block b scans cnt[b*NT..] -> cursor, and writes dinv (dgi/dci contiguous)
__global__ __launch_bounds__(1024) void k_scan2(const int* __restrict__ cnt,
                                                int* __restrict__ cur,
                                                float* __restrict__ dinv){
  __shared__ int part[1024];
  const int off = blockIdx.x * NT;
  const int tid = threadIdx.x;
  const int base = tid*32;
  int s = 0;
  for (int i=0;i<32;i++){
    const int c = cnt[off + base + i];
    dinv[off + base + i] = 1.0f / (float)(c > 1 ? c : 1);
    s += c;
  }
  const int own = s;
  part[tid] = s; __syncthreads();
  for (int o=1; o<1024; o<<=1){
    int v = (tid>=o) ? part[tid-o] : 0;
    __syncthreads();
    part[tid] += v;
    __syncthreads();
  }
  int run = part[tid] - own;
  for (int i=0;i<32;i++){ cur[off + base + i] = run; run += cnt[off + base + i]; }
}

// writes dst-sorted (src,dst) pairs -> k_edge needs ONE load to get both ids
__global__ __launch_bounds__(256) void k_scatter2(const int* __restrict__ esrc,
                                                  const int* __restrict__ edst,
                                                  const int* __restrict__ csrc,
                                                  const int* __restrict__ cdst,
                                                  int* __restrict__ cur,
                                                  int2* __restrict__ sd){
  const int half = blockIdx.x >= (NE/256);
  const int e = (blockIdx.x - half*(NE/256))*256 + threadIdx.x;
  const int* sA = half ? csrc : esrc;
  const int* dA = half ? cdst : edst;
  const int dv = dA[e];
  const int p = atomicAdd(&cur[half*NT + dv], 1);
  int2 v; v.x = sA[e]; v.y = dv;
  sd[half*NE + p] = v;
}

// ---------------- node-side MFMA GEMM: 64 rows/block, 512 blocks, 8 waves, NO LDS/barriers ----
// Waves = 4 row-tiles x 2 groups. Group = col-half (MODE 0/2/3) or output matrix (MODE 1).
// B-fragments are read directly from the L2-resident packed weights (16B/lane coalesced).
// MODE 0: embed  (A=feat, K=128, out h & h0)
// MODE 1: proj2  (A=h, K=128, grp0 -> Aw=h@We1a+be1, grp1 -> Bw=h@We1b)
// MODE 2: hupd1  (A=[h|aggm*dinv|h0], K=384, out c1 = silu(.+bh); zeroes aggm at end)
// MODE 3: hupd2  (same, out h = silu(.+bh) - c1; zeroes aggm at end)
template<int MODE>
__global__ __launch_bounds__(512) void k_ngemm(
    const float* __restrict__ A0, float* __restrict__ A1, const float* __restrict__ A2,
    const float* __restrict__ dinv, const short* __restrict__ W0, const short* __restrict__ W1,
    const float* __restrict__ bias, const float* __restrict__ c1in,
    float* __restrict__ out0, float* __restrict__ out1)
{
  const int tid = threadIdx.x;
  const int wv = tid>>6, lane = tid&63, c = lane&15, q = lane>>4;
  const int rowt = wv & 3, grp = wv >> 2;
  const int row = blockIdx.x*64 + rowt*16 + c;
  constexpr int KC = (MODE>=2) ? 12 : 4;
  constexpr int TT = (MODE==1) ? 8 : 4;
  float dv = 1.0f;
  if constexpr (MODE>=2) dv = dinv[row];
  const short* Wp = W0;
  if constexpr (MODE==1){ if (grp==1) Wp = W1; }
  f32x4 acc[TT];
  #pragma unroll
  for (int t=0;t<TT;t++){ acc[t][0]=0.f; acc[t][1]=0.f; acc[t][2]=0.f; acc[t][3]=0.f; }

  #pragma unroll
  for (int kc=0; kc<KC; ++kc){
    const float* asrc = A0; float sc = 1.0f;
    if constexpr (MODE>=2){
      if (kc >= 8)      { asrc = A2; }
      else if (kc >= 4) { asrc = A1; sc = dv; }
    }
    const int koff = (kc&3)*32 + q*8;
    float4 v0 = *(const float4*)(asrc + (size_t)row*128 + koff);
    float4 v1 = *(const float4*)(asrc + (size_t)row*128 + koff + 4);
    float m[8] = {v0.x*sc,v0.y*sc,v0.z*sc,v0.w*sc,v1.x*sc,v1.y*sc,v1.z*sc,v1.w*sc};
    bf16x8 ah, al; split8(m, ah, al);
    #pragma unroll
    for (int t=0;t<TT;t++){
      const int tg = (MODE==1) ? t : grp*4 + t;
      const short* fp = Wp + (size_t)kc*8192 + q*1024 + (tg*16 + c)*8;
      bf16x8 bh = *(const bf16x8*)fp;
      bf16x8 bl = *(const bf16x8*)(fp + 4096);
      acc[t] = mma3(ah, al, bh, bl, acc[t]);
    }
  }
  // epilogue: C row = blk*64 + rowt*16 + q*4 + r, col = tg*16 + c
  #pragma unroll
  for (int t=0;t<TT;t++){
    const int tg = (MODE==1) ? t : grp*4 + t;
    const int col = tg*16 + c;
    float b0 = 0.f;
    if constexpr (MODE==1){ if (grp==0) b0 = bias[col]; }
    else if constexpr (MODE>=2){ b0 = bias[col]; }
    #pragma unroll
    for (int r=0;r<4;r++){
      const size_t orow = (size_t)blockIdx.x*64 + rowt*16 + q*4 + r;
      float v = acc[t][r];
      if constexpr (MODE==0){
        out0[orow*128 + col] = v; out1[orow*128 + col] = v;
      } else if constexpr (MODE==1){
        if (grp==0) out0[orow*128 + col] = v + b0;
        else        out1[orow*128 + col] = v;
      } else if constexpr (MODE==2){
        out0[orow*128 + col] = siluf(v + b0);
      } else {
        out0[orow*128 + col] = siluf(v + b0) - c1in[orow*128 + col];
      }
    }
  }
  if constexpr (MODE>=2){
    // consume-and-zero this block's aggm rows (block-exclusive; all reads done above)
    __syncthreads();
    float4 z; z.x=0.f; z.y=0.f; z.z=0.f; z.w=0.f;
    float4* zp = (float4*)(A1 + (size_t)blockIdx.x*64*128);
    #pragma unroll
    for (int i=0;i<4;i++) zp[tid + i*512] = z;
  }
}

// ---------------- fused edge MLP (MFMA) + scatter: 128 dst-sorted edges per block ----------------
// Occupancy-restructured: LDS holds only the We2 HI plane (32 KB; lo-plane streams from
// global and becomes L1-resident), kc-outer loop keeps ~60 VGPR peak, launch_bounds(512,8)
// pins <=64 VGPR -> 4 blocks/CU (was 2) so wave-level TLP hides gather/atomic latency.
__global__ __launch_bounds__(512, 8) void k_edge(
    const int2* __restrict__ sd, const float* __restrict__ x,
    const float* __restrict__ Aw, const float* __restrict__ Bw,
    const short* __restrict__ w2p, const float* __restrict__ We1_l,
    const float* __restrict__ be2_l, const float* __restrict__ Wx_l,
    float* __restrict__ aggm, float* __restrict__ aggx)
{
  __shared__ __align__(16) short w2t[16384];   // 32 KB: We2 hi-plane, [kc][4096]
  __shared__ __align__(16) float w256s[128];
  __shared__ __align__(16) float wxs[128];
  __shared__ __align__(16) float be2s[128];
  __shared__ float dxs[8][16][3];              // per-wave scratch (intra-wave only)
  __shared__ int   dsts[8][16];
  const int tid = threadIdx.x;
  const int wv = tid>>6, lane = tid&63, c = lane&15, q = lane>>4;
  const int er = wv*16 + c;
  // edge pair: single coalesced load
  const int2 sdv = sd[blockIdx.x*128 + er];
  // async-stage hi-plane: chunk kc=i, lane covers (tid&511)*8 shorts within the chunk
  #pragma unroll
  for (int i=0;i<4;i++)
    GLOAD_LDS16(w2p + (size_t)i*8192 + tid*8, w2t + i*4096 + wv*512);
  if (tid < 128){ w256s[tid]=We1_l[256*128+tid]; wxs[tid]=Wx_l[tid]; be2s[tid]=be2_l[tid]; }
  const int s = sdv.x, d = sdv.y;
  const float xs0=x[s*3+0], xs1=x[s*3+1], xs2=x[s*3+2];
  const float xd0=x[d*3+0], xd1=x[d*3+1], xd2=x[d*3+2];
  const float dx0 = xs0-xd0, dx1 = xs1-xd1, dx2 = xs2-xd2;
  const float d2  = dx0*dx0 + dx1*dx1 + dx2*dx2;
  if (q==0){ dxs[wv][c][0]=dx0; dxs[wv][c][1]=dx1; dxs[wv][c][2]=dx2; dsts[wv][c]=d; }
  __syncthreads();   // the only barrier: drains staging + pre-issued loads

  const float* ap = Aw + (size_t)s*128 + q*8;
  const float* bp = Bw + (size_t)d*128 + q*8;
  const short* lo = w2p + 4096 + q*1024 + c*8;   // lo-plane base for this lane
  f32x4 acc[8];
  #pragma unroll
  for (int t=0;t<8;t++){ acc[t][0]=0.f; acc[t][1]=0.f; acc[t][2]=0.f; acc[t][3]=0.f; }
  #pragma unroll
  for (int kc=0; kc<4; ++kc){
    const int kb = kc*32 + q*8;
    float4 av0 = *(const float4*)(ap + kc*32), av1 = *(const float4*)(ap + kc*32 + 4);
    float4 bv0 = *(const float4*)(bp + kc*32), bv1 = *(const float4*)(bp + kc*32 + 4);
    float4 w0  = *(const float4*)&w256s[kb],   w1  = *(const float4*)&w256s[kb+4];
    float m[8];
    m[0]=siluf(av0.x+bv0.x+d2*w0.x); m[1]=siluf(av0.y+bv0.y+d2*w0.y);
    m[2]=siluf(av0.z+bv0.z+d2*w0.z); m[3]=siluf(av0.w+bv0.w+d2*w0.w);
    m[4]=siluf(av1.x+bv1.x+d2*w1.x); m[5]=siluf(av1.y+bv1.y+d2*w1.y);
    m[6]=siluf(av1.z+bv1.z+d2*w1.z); m[7]=siluf(av1.w+bv1.w+d2*w1.w);
    bf16x8 ah, al; split8(m, ah, al);
    #pragma unroll
    for (int t=0;t<8;t++){
      bf16x8 bh = *(const bf16x8*)&w2t[kc*4096 + q*1024 + (t*16 + c)*8];
      bf16x8 bl = *(const bf16x8*)(lo + (size_t)kc*8192 + t*128);
      acc[t] = mma3(ah, al, bh, bl, acc[t]);
    }
  }
  // epilogue: edge row (in wave tile) = q*4 + r, col = t*16 + c
  const int rb = q*4;
  const int rd0 = dsts[wv][rb+0], rd1 = dsts[wv][rb+1];
  const int rd2 = dsts[wv][rb+2], rd3 = dsts[wv][rb+3];
  const bool b1 = (rd1!=rd0), b2 = (rd2!=rd1), b3 = (rd3!=rd2);
  float pd[4] = {0.f, 0.f, 0.f, 0.f};
  #pragma unroll
  for (int t=0;t<8;t++){
    const int col = t*16 + c;
    const float be = be2s[col], wx = wxs[col];
    #pragma unroll
    for (int r=0;r<4;r++){
      float v = siluf(acc[t][r] + be);
      acc[t][r] = v;
      pd[r] += v*wx;
    }
    // static suffix-sum run compression
    float v3 = acc[t][3];
    float v2 = acc[t][2] + (b3 ? 0.f : v3);
    float v1 = acc[t][1] + (b2 ? 0.f : v2);
    float v0 = acc[t][0] + (b1 ? 0.f : v1);
    unsafeAtomicAdd(aggm + (size_t)rd0*128 + col, v0);
    if (b1) unsafeAtomicAdd(aggm + (size_t)rd1*128 + col, v1);
    if (b2) unsafeAtomicAdd(aggm + (size_t)rd2*128 + col, v2);
    if (b3) unsafeAtomicAdd(aggm + (size_t)rd3*128 + col, v3);
  }
  #pragma unroll
  for (int msk=1; msk<16; msk<<=1){
    #pragma unroll
    for (int r=0;r<4;r++) pd[r] += __shfl_xor(pd[r], msk);
  }
  if (c < 3){ // agg_x scatter, component c
    float a0 = dxs[wv][rb+0][c]*tanh_fast(pd[0]);
    float a1 = dxs[wv][rb+1][c]*tanh_fast(pd[1]);
    float a2 = dxs[wv][rb+2][c]*tanh_fast(pd[2]);
    float a3 = dxs[wv][rb+3][c]*tanh_fast(pd[3]);
    float v3 = a3;
    float v2 = a2 + (b3 ? 0.f : v3);
    float v1 = a1 + (b2 ? 0.f : v2);
    float v0 = a0 + (b1 ? 0.f : v1);
    unsafeAtomicAdd(aggx + (size_t)rd0*3 + c, v0);
    if (b1) unsafeAtomicAdd(aggx + (size_t)rd1*3 + c, v1);
    if (b2) unsafeAtomicAdd(aggx + (size_t)rd2*3 + c, v2);
    if (b3) unsafeAtomicAdd(aggx + (size_t)rd3*3 + c, v3);
  }
}

// ---------------- coordinate update (consume-and-zero aggx) ----------------
__global__ __launch_bounds__(256) void k_xupd(float* __restrict__ x, const float* __restrict__ x0,
                                              float* __restrict__ aggx,
                                              const float* __restrict__ dinv){
  int i = blockIdx.x*256 + threadIdx.x;
  if (i < NT*3){
    int n = i/3;
    x[i] = 0.25f*x0[i] + 0.75f*x[i] + aggx[i]*dinv[n];
    aggx[i] = 0.f;
  }
}

// ---------------- masked mean pool (4-slice parallel) ----------------
__global__ __launch_bounds__(512) void k_pool(const float* __restrict__ h,
                                              const float* __restrict__ cvalid,
                                              float* __restrict__ pooled){
  __shared__ float red[4][128];
  __shared__ float redc[4];
  const int b = blockIdx.x, t = threadIdx.x, j = t&127, sl = t>>7;
  float s = 0.f, cf = 0.f;
  for (int n=sl; n<NPG; n+=4){
    const float m = cvalid[b*NPG + n];
    s  += h[((size_t)b*NPG + n)*DH + j] * m;
    cf += m;
  }
  red[sl][j] = s;
  if (j==0) redc[sl] = cf;
  __syncthreads();
  if (t < 128){
    float ss = red[0][t]+red[1][t]+red[2][t]+red[3][t];
    float cc = redc[0]+redc[1]+redc[2]+redc[3];
    pooled[b*DH + t] = ss / cc;
  }
}

// ---------------- final MLP head (single block) ----------------
__global__ __launch_bounds__(256) void k_mlp(const float* __restrict__ pooled,
                                             const float* __restrict__ Wfc,
                                             const float* __restrict__ bfc,
                                             const float* __restrict__ Wout,
                                             const float* __restrict__ bout,
                                             float* __restrict__ out)
{
  __shared__ __align__(16) float z[64*132];
  __shared__ __align__(16) float wB[128*128];
  const int t = threadIdx.x;
  {
    const int n = t>>2, qq = t&3;
    const float4* p = (const float4*)(pooled + n*DH + qq*32);
    float4* w = (float4*)&z[n*132 + qq*32];
    #pragma unroll
    for (int u=0;u<8;u++) w[u] = p[u];
  }
  const int g = t>>5, lane = t&31, c0 = lane*4;
  for (int l=0;l<3;l++){
    #pragma unroll
    for (int i=0;i<16;i++){
      const int idx = t + i*256;
      ((float4*)wB)[idx] = ((const float4*)(Wfc + (size_t)l*DH*DH))[idx];
    }
    __syncthreads();
    float acc[8][4];
    #pragma unroll
    for (int i=0;i<8;i++){ acc[i][0]=0.f; acc[i][1]=0.f; acc[i][2]=0.f; acc[i][3]=0.f; }
    #pragma unroll 4
    for (int kk=0; kk<128; kk+=4){
      float4 b0=*(const float4*)&wB[(kk+0)*128+c0];
      float4 b1=*(const float4*)&wB[(kk+1)*128+c0];
      float4 b2=*(const float4*)&wB[(kk+2)*128+c0];
      float4 b3=*(const float4*)&wB[(kk+3)*128+c0];
      #pragma unroll
      for (int i=0;i<8;i++){
        float4 a=*(const float4*)&z[(g*8+i)*132 + kk];
        acc[i][0]+=a.x*b0.x+a.y*b1.x+a.z*b2.x+a.w*b3.x;
        acc[i][1]+=a.x*b0.y+a.y*b1.y+a.z*b2.y+a.w*b3.y;
        acc[i][2]+=a.x*b0.z+a.y*b1.z+a.z*b2.z+a.w*b3.z;
        acc[i][3]+=a.x*b0.w+a.y*b1.w+a.z*b2.w+a.w*b3.w;
      }
    }
    __syncthreads();
    #pragma unroll
    for (int i=0;i<8;i++){
      float v0=acc[i][0]+bfc[l*DH+c0+0]; v0 = v0>0.f?v0:0.f;
      float v1=acc[i][1]+bfc[l*DH+c0+1]; v1 = v1>0.f?v1:0.f;
      float v2=acc[i][2]+bfc[l*DH+c0+2]; v2 = v2>0.f?v2:0.f;
      float v3=acc[i][3]+bfc[l*DH+c0+3]; v3 = v3>0.f?v3:0.f;
      float4 v; v.x=v0; v.y=v1; v.z=v2; v.w=v3;
      *(float4*)&z[(g*8+i)*132 + c0] = v;
    }
    __syncthreads();
  }
  if (t < 64){
    float a = 0.f;
    for (int k2=0;k2<128;k2++) a += z[t*132 + k2]*Wout[k2];
    out[t] = 1.0f/(1.0f + __expf(-(a + bout[0])));
  }
}

// ---------------- host ----------------
extern "C" void kernel_launch(void* const* d_in, const int* in_sizes, int n_in,
                              void* d_out, int out_size, void* d_ws, size_t ws_size,
                              hipStream_t stream)
{
  (void)in_sizes; (void)n_in; (void)out_size; (void)ws_size;
  const float* feat   = (const float*)d_in[0];
  const float* coords = (const float*)d_in[1];
  const float* cvalid = (const float*)d_in[2];
  const int*   esrc   = (const int*)d_in[3];
  const int*   edst   = (const int*)d_in[4];
  const int*   csrc   = (const int*)d_in[5];
  const int*   cdst   = (const int*)d_in[6];
  const float* W_emb  = (const float*)d_in[7];
  const float* We1    = (const float*)d_in[8];
  const float* be1    = (const float*)d_in[9];
  const float* We2    = (const float*)d_in[10];
  const float* be2    = (const float*)d_in[11];
  const float* Wx     = (const float*)d_in[12];
  const float* Wh     = (const float*)d_in[13];
  const float* bh     = (const float*)d_in[14];
  const float* Wfc    = (const float*)d_in[15];
  const float* bfc    = (const float*)d_in[16];
  const float* Wout   = (const float*)d_in[17];
  const float* bout   = (const float*)d_in[18];

  float* ws = (float*)d_ws;
  float* h      = ws; ws += (size_t)NT*DH;
  float* h0     = ws; ws += (size_t)NT*DH;
  float* c1     = ws; ws += (size_t)NT*DH;
  float* Aw     = ws; ws += (size_t)NT*DH;
  float* Bw     = ws; ws += (size_t)NT*DH;
  float* aggm   = ws; ws += (size_t)NT*DH;   // aggm & aggx adjacent -> single memset
  float* aggx   = ws; ws += (size_t)NT*3;
  float* x      = ws; ws += (size_t)NT*3;
  float* dgi    = ws; ws += NT;              // dgi & dci adjacent (scan2 indexes both)
  float* dci    = ws; ws += NT;
  float* pooled = ws; ws += BGR*DH;
  int2* sdG   = (int2*)ws; ws += (size_t)4*NE;  // 2*NE int2: graph pairs then cross pairs
  // cnt/cursor overlay c1 (sort phase finishes before c1 is first written)
  int* cnt    = (int*)c1;          // 2*NT
  int* cursor = cnt + 2*NT;        // 2*NT
  // split-plane packed weight arena (bf16 shorts)
  short* pst    = (short*)ws;
  short* wemb_p = pst;                       // K=128 -> 4 chunks -> 32768 shorts
  short* lay_p  = pst + 32768;

  // ---- zero accumulators once (consumers re-zero afterwards); aggm+aggx contiguous ----
  hipMemsetAsync(aggm, 0, (size_t)NT*(DH+3)*sizeof(float), stream);

  // ---- weight prep: single launch for all 16 matrices ----
  k_prep_all<<<1984, 256, 0, stream>>>(W_emb, We1, We2, Wh, wemb_p, lay_p);

  // ---- dst-sort both edge sets + degree inverses (4 launches total) ----
  hipMemsetAsync(cnt, 0, 2*NT*sizeof(int), stream);
  k_hist2   <<<2*(NE/256), 256, 0, stream>>>(edst, cdst, cnt);
  k_scan2   <<<2, 1024, 0, stream>>>(cnt, cursor, dgi);
  k_scatter2<<<2*(NE/256), 256, 0, stream>>>(esrc, edst, csrc, cdst, cursor, sdG);

  // ---- embedding: h = feat @ W_emb^T ; h0 = h ; x = coords ----
  k_ngemm<0><<<NT/64, 512, 0, stream>>>(feat, nullptr, nullptr, nullptr,
                                        wemb_p, nullptr, nullptr, nullptr, h, h0);
  hipMemcpyAsync(x, coords, (size_t)NT*3*sizeof(float), hipMemcpyDeviceToDevice, stream);

  for (int k=0; k<LAYS; k++){
    short* p = lay_p + (size_t)k*LSTR;
    const float* We1_l = We1 + (size_t)k*257*DH;
    const float* be1_l = be1 + (size_t)k*DH;
    const float* be2_l = be2 + (size_t)k*DH;
    const float* Wx_l  = Wx  + (size_t)k*DH;
    const float* bh_l  = bh  + (size_t)k*DH;

    // node-side hoist of edge-MLP layer 1 (shared by graph & cross calls)
    k_ngemm<1><<<NT/64, 512, 0, stream>>>(h, nullptr, nullptr, nullptr,
                                          p, p + 32768, be1_l, nullptr, Aw, Bw);
    // --- graph edges ---
    k_edge<<<NE/128, 512, 0, stream>>>(sdG, x, Aw, Bw,
                                       p + 65536, We1_l, be2_l, Wx_l, aggm, aggx);
    k_xupd<<<(NT*3+255)/256, 256, 0, stream>>>(x, coords, aggx, dgi);
    k_ngemm<2><<<NT/64, 512, 0, stream>>>(h, aggm, h0, dgi,
                                          p + 98304, nullptr, bh_l, nullptr, c1, nullptr);
    // --- cross edges ---
    k_edge<<<NE/128, 512, 0, stream>>>(sdG + NE, x, Aw, Bw,
                                       p + 65536, We1_l, be2_l, Wx_l, aggm, aggx);
    k_xupd<<<(NT*3+255)/256, 256, 0, stream>>>(x, coords, aggx, dci);
    k_ngemm<3><<<NT/64, 512, 0, stream>>>(h, aggm, h0, dci,
                                          p + 98304, nullptr, bh_l, c1, h, nullptr);
  }

  k_pool<<<BGR, 512, 0, stream>>>(h, cvalid, pooled);
  k_mlp <<<1, 256, 0, stream>>>(pooled, Wfc, bfc, Wout, bout, (float*)d_out);
}

// Round 9
// 1693.287 us; speedup vs baseline: 1.1851x; 1.1851x over previous
//
#include <hip/hip_runtime.h>

#define DEVINL __device__ __forceinline__

constexpr int NT   = 32768;   // 64*512 nodes
constexpr int DH   = 128;
constexpr int NE   = 262144;
constexpr int BGR  = 64;
constexpr int NPG  = 512;
constexpr int LAYS = 5;
constexpr size_t LSTR = 32768*3 + 98304;   // per-layer packed: we1a, we1b, we2, wh

typedef __attribute__((ext_vector_type(8))) short bf16x8;
typedef __attribute__((ext_vector_type(4))) float f32x4;
typedef __attribute__((ext_vector_type(4))) unsigned int uint4v;
typedef unsigned int uint;

DEVINL float siluf(float v){ return v * (1.0f/(1.0f + __expf(-v))); }
DEVINL float tanh_fast(float x){ float e = __expf(2.0f*x); return 1.0f - 2.0f/(e + 1.0f); }

DEVINL uint bf16_rne(float f){
  uint x = __float_as_uint(f);
  return (x + 0x7fffu + ((x>>16)&1u)) >> 16;
}

// split one f32 into hi (truncated bf16) + lo (rne bf16 of residual): ~16-bit mantissa total
DEVINL void split8(const float* m, bf16x8& h, bf16x8& l){
  #pragma unroll
  for (int j=0;j<8;j++){
    uint x  = __float_as_uint(m[j]);
    uint hb = x >> 16;
    float hf = __uint_as_float(hb<<16);
    uint lb = bf16_rne(m[j] - hf);
    h[j] = (short)hb; l[j] = (short)lb;
  }
}

// 3-term split-bf16 MFMA accumulate: acc += A*B with ~f32 precision (drops al*bl)
DEVINL f32x4 mma3(bf16x8 ah, bf16x8 al, bf16x8 bh, bf16x8 bl, f32x4 acc){
  acc = __builtin_amdgcn_mfma_f32_16x16x32_bf16(al, bh, acc, 0,0,0);
  acc = __builtin_amdgcn_mfma_f32_16x16x32_bf16(ah, bl, acc, 0,0,0);
  acc = __builtin_amdgcn_mfma_f32_16x16x32_bf16(ah, bh, acc, 0,0,0);
  return acc;
}

#define GLOAD_LDS16(g, l) __builtin_amdgcn_global_load_lds( \
    (const __attribute__((address_space(1))) void*)(g), \
    (__attribute__((address_space(3))) void*)(l), 16, 0, 0)

// ---------------- fused weight prep: all 16 weight matrices in ONE launch ----------------
__global__ __launch_bounds__(256) void k_prep_all(
    const float* __restrict__ W_emb, const float* __restrict__ We1,
    const float* __restrict__ We2,  const float* __restrict__ Wh,
    short* __restrict__ wemb_p, short* __restrict__ lay_p)
{
  const int idx = blockIdx.x*256 + threadIdx.x;
  const float* src; short* dst; int v; bool trans = false;
  if (idx < 16384){ src = W_emb; dst = wemb_p; v = idx; trans = true; }
  else {
    const int u = idx - 16384;
    const int layer = u / 98304;
    const int w = u - layer*98304;
    short* p = lay_p + (size_t)layer*LSTR;
    if (w < 16384)      { src = We1 + (size_t)layer*257*DH;          dst = p;         v = w; }
    else if (w < 32768) { src = We1 + (size_t)layer*257*DH + 128*DH; dst = p + 32768; v = w - 16384; }
    else if (w < 49152) { src = We2 + (size_t)layer*DH*DH;           dst = p + 65536; v = w - 32768; }
    else                { src = Wh  + (size_t)layer*3*DH*DH;         dst = p + 98304; v = w - 49152; }
  }
  const int k = v>>7, col = v&127;
  const float val = trans ? src[(size_t)col*128 + k] : src[(size_t)k*128 + col];
  uint hb = __float_as_uint(val) >> 16;
  float hf = __uint_as_float(hb<<16);
  uint lb = bf16_rne(val - hf);
  const int kc = k>>5, q = (k&31)>>3, j = k&7;
  const size_t o = (size_t)kc*8192 + q*1024 + col*8 + j;
  dst[o]        = (short)hb;
  dst[o + 4096] = (short)lb;
}

// ---------------- sort / degree (both edge sets per launch) ----------------
__global__ __launch_bounds__(256) void k_hist2(const int* __restrict__ edst,
                                               const int* __restrict__ cdst,
                                               int* __restrict__ cnt){
  const int half = blockIdx.x >= (NE/256);
  const int e = (blockIdx.x - half*(NE/256))*256 + threadIdx.x;
  const int* d = half ? cdst : edst;
  atomicAdd(&cnt[half*NT + d[e]], 1);
}

__global__ __launch_bounds__(1024) void k_scan2(const int* __restrict__ cnt,
                                                int* __restrict__ cur,
                                                float* __restrict__ dinv){
  __shared__ int part[1024];
  const int off = blockIdx.x * NT;
  const int tid = threadIdx.x;
  const int base = tid*32;
  int s = 0;
  for (int i=0;i<32;i++){
    const int c = cnt[off + base + i];
    dinv[off + base + i] = 1.0f / (float)(c > 1 ? c : 1);
    s += c;
  }
  const int own = s;
  part[tid] = s; __syncthreads();
  for (int o=1; o<1024; o<<=1){
    int v = (tid>=o) ? part[tid-o] : 0;
    __syncthreads();
    part[tid] += v;
    __syncthreads();
  }
  int run = part[tid] - own;
  for (int i=0;i<32;i++){ cur[off + base + i] = run; run += cnt[off + base + i]; }
}

// writes dst-sorted (src,dst) pairs -> k_edge needs ONE load to get both ids
__global__ __launch_bounds__(256) void k_scatter2(const int* __restrict__ esrc,
                                                  const int* __restrict__ edst,
                                                  const int* __restrict__ csrc,
                                                  const int* __restrict__ cdst,
                                                  int* __restrict__ cur,
                                                  int2* __restrict__ sd){
  const int half = blockIdx.x >= (NE/256);
  const int e = (blockIdx.x - half*(NE/256))*256 + threadIdx.x;
  const int* sA = half ? csrc : esrc;
  const int* dA = half ? cdst : edst;
  const int dv = dA[e];
  const int p = atomicAdd(&cur[half*NT + dv], 1);
  int2 v; v.x = sA[e]; v.y = dv;
  sd[half*NE + p] = v;
}

// ---------------- node-side MFMA GEMM: 64 rows/block, 512 blocks, 8 waves, NO LDS/barriers ----
// MODE 0: embed  (A=feat, K=128, out h & h0)
// MODE 1: proj2  (A=h, K=128, grp0 -> Aw=h@We1a+be1, grp1 -> Bw=h@We1b)
// MODE 2: hupd1  (A=[h|aggm*dinv|h0], K=384, out c1; fused x-update+aggx-zero; zeroes aggm)
// MODE 3: hupd2  (same, out h = silu(.+bh) - c1; fused x-update; zeroes aggm)
// Register double-buffer on the A row-chunk (prefetch kc+1 before MFMAs of kc).
template<int MODE>
__global__ __launch_bounds__(512) void k_ngemm(
    const float* __restrict__ A0, float* __restrict__ A1, const float* __restrict__ A2,
    const float* __restrict__ dinv, const short* __restrict__ W0, const short* __restrict__ W1,
    const float* __restrict__ bias, const float* __restrict__ c1in,
    float* __restrict__ out0, float* __restrict__ out1,
    float* __restrict__ xv, const float* __restrict__ x0, float* __restrict__ aggx)
{
  const int tid = threadIdx.x;
  const int wv = tid>>6, lane = tid&63, c = lane&15, q = lane>>4;
  const int rowt = wv & 3, grp = wv >> 2;
  const int row = blockIdx.x*64 + rowt*16 + c;
  constexpr int KC = (MODE>=2) ? 12 : 4;
  constexpr int TT = (MODE==1) ? 8 : 4;
  if constexpr (MODE>=2){
    // fused coordinate update for this block's 64 exclusive nodes (replaces k_xupd)
    if (tid < 192){
      const int i = blockIdx.x*192 + tid;
      const int nn = i/3;
      xv[i] = 0.25f*x0[i] + 0.75f*xv[i] + aggx[i]*dinv[nn];
      aggx[i] = 0.f;
    }
  }
  float dv = 1.0f;
  if constexpr (MODE>=2) dv = dinv[row];
  const short* Wp = W0;
  if constexpr (MODE==1){ if (grp==1) Wp = W1; }
  f32x4 acc[TT];
  #pragma unroll
  for (int t=0;t<TT;t++){ acc[t][0]=0.f; acc[t][1]=0.f; acc[t][2]=0.f; acc[t][3]=0.f; }

  auto aload = [&](int kc, float4& v0, float4& v1){
    const float* asrc = A0;
    if constexpr (MODE>=2){
      if (kc >= 8)      { asrc = A2; }
      else if (kc >= 4) { asrc = A1; }
    }
    const int koff = (kc&3)*32 + q*8;
    v0 = *(const float4*)(asrc + (size_t)row*128 + koff);
    v1 = *(const float4*)(asrc + (size_t)row*128 + koff + 4);
  };

  float4 v0c, v1c, v0n, v1n;
  aload(0, v0c, v1c);
  #pragma unroll
  for (int kc=0; kc<KC; ++kc){
    if (kc+1 < KC) aload(kc+1, v0n, v1n);   // prefetch next A chunk
    float sc = 1.0f;
    if constexpr (MODE>=2){ if (kc >= 4 && kc < 8) sc = dv; }
    float m[8] = {v0c.x*sc,v0c.y*sc,v0c.z*sc,v0c.w*sc,v1c.x*sc,v1c.y*sc,v1c.z*sc,v1c.w*sc};
    bf16x8 ah, al; split8(m, ah, al);
    #pragma unroll
    for (int t=0;t<TT;t++){
      const int tg = (MODE==1) ? t : grp*4 + t;
      const short* fp = Wp + (size_t)kc*8192 + q*1024 + (tg*16 + c)*8;
      bf16x8 bh = *(const bf16x8*)fp;
      bf16x8 bl = *(const bf16x8*)(fp + 4096);
      acc[t] = mma3(ah, al, bh, bl, acc[t]);
    }
    v0c = v0n; v1c = v1n;
  }
  // epilogue: C row = blk*64 + rowt*16 + q*4 + r, col = tg*16 + c
  #pragma unroll
  for (int t=0;t<TT;t++){
    const int tg = (MODE==1) ? t : grp*4 + t;
    const int col = tg*16 + c;
    float b0 = 0.f;
    if constexpr (MODE==1){ if (grp==0) b0 = bias[col]; }
    else if constexpr (MODE>=2){ b0 = bias[col]; }
    #pragma unroll
    for (int r=0;r<4;r++){
      const size_t orow = (size_t)blockIdx.x*64 + rowt*16 + q*4 + r;
      float v = acc[t][r];
      if constexpr (MODE==0){
        out0[orow*128 + col] = v; out1[orow*128 + col] = v;
      } else if constexpr (MODE==1){
        if (grp==0) out0[orow*128 + col] = v + b0;
        else        out1[orow*128 + col] = v;
      } else if constexpr (MODE==2){
        out0[orow*128 + col] = siluf(v + b0);
      } else {
        out0[orow*128 + col] = siluf(v + b0) - c1in[orow*128 + col];
      }
    }
  }
  if constexpr (MODE>=2){
    // consume-and-zero this block's aggm rows (block-exclusive; all reads done above)
    __syncthreads();
    float4 z; z.x=0.f; z.y=0.f; z.z=0.f; z.w=0.f;
    float4* zp = (float4*)(A1 + (size_t)blockIdx.x*64*128);
    #pragma unroll
    for (int i=0;i<4;i++) zp[tid + i*512] = z;
  }
}

// ---------------- fused edge MLP (MFMA) + scatter: 128 dst-sorted edges per block ----------------
// FROZEN R7 champion (105 us). R8 lesson: raising occupancy (4 blocks/CU) widens the resident
// dst-window -> active aggm lines exceed per-XCD L2 -> atomic write-backs to HBM (WRITE 60->261MB)
// AND tight VGPR bounds spill. 2 blocks/CU + single barrier + pre-issued gathers is the optimum
// found for this structure; do NOT chase occupancy here.
__global__ __launch_bounds__(512, 4) void k_edge(
    const int2* __restrict__ sd, const float* __restrict__ x,
    const float* __restrict__ Aw, const float* __restrict__ Bw,
    const short* __restrict__ w2p, const float* __restrict__ We1_l,
    const float* __restrict__ be2_l, const float* __restrict__ Wx_l,
    float* __restrict__ aggm, float* __restrict__ aggx)
{
  __shared__ __align__(16) short w2t[32768];   // 64 KB: full We2 (4 chunks x hi/lo)
  __shared__ __align__(16) float w256s[128];
  __shared__ __align__(16) float wxs[128];
  __shared__ __align__(16) float be2s[128];
  __shared__ float dxs[8][16][3];              // per-wave scratch (intra-wave only)
  __shared__ int   dsts[8][16];
  const int tid = threadIdx.x;
  const int wv = tid>>6, lane = tid&63, c = lane&15, q = lane>>4;
  const int er = wv*16 + c;
  // (1) edge pair: single coalesced load, oldest in the vmem queue
  const int2 sdv = sd[blockIdx.x*128 + er];
  // (2) async-stage full We2 directly into LDS (wave-uniform base + lane*16 pattern)
  #pragma unroll
  for (int i=0;i<8;i++)
    GLOAD_LDS16(w2p + (size_t)(tid + i*512)*8, w2t + (size_t)(wv*64 + i*512)*8);
  if (tid < 128){ w256s[tid]=We1_l[256*128+tid]; wxs[tid]=Wx_l[tid]; be2s[tid]=be2_l[tid]; }
  const int s = sdv.x, d = sdv.y;
  // (3) issue ALL gathers now; they land by the barrier
  const float xs0=x[s*3+0], xs1=x[s*3+1], xs2=x[s*3+2];
  const float xd0=x[d*3+0], xd1=x[d*3+1], xd2=x[d*3+2];
  const float* ap = Aw + (size_t)s*128 + q*8;
  const float* bp = Bw + (size_t)d*128 + q*8;
  float4 aa[8], bb[8];
  #pragma unroll
  for (int kc=0;kc<4;kc++){
    aa[2*kc]   = *(const float4*)(ap + kc*32);
    aa[2*kc+1] = *(const float4*)(ap + kc*32 + 4);
    bb[2*kc]   = *(const float4*)(bp + kc*32);
    bb[2*kc+1] = *(const float4*)(bp + kc*32 + 4);
  }
  const float dx0 = xs0-xd0, dx1 = xs1-xd1, dx2 = xs2-xd2;
  const float d2  = dx0*dx0 + dx1*dx1 + dx2*dx2;
  if (q==0){ dxs[wv][c][0]=dx0; dxs[wv][c][1]=dx1; dxs[wv][c][2]=dx2; dsts[wv][c]=d; }
  __syncthreads();   // the ONLY barrier: drains staging + gathers

  // m1 fragments for all 4 k-chunks (pure VALU now)
  bf16x8 ah[4], al[4];
  #pragma unroll
  for (int kc=0;kc<4;kc++){
    const int kb = kc*32 + q*8;
    float4 w0 = *(const float4*)&w256s[kb], w1 = *(const float4*)&w256s[kb+4];
    float4 av0=aa[2*kc], av1=aa[2*kc+1], bv0=bb[2*kc], bv1=bb[2*kc+1];
    float m[8];
    m[0]=siluf(av0.x+bv0.x+d2*w0.x); m[1]=siluf(av0.y+bv0.y+d2*w0.y);
    m[2]=siluf(av0.z+bv0.z+d2*w0.z); m[3]=siluf(av0.w+bv0.w+d2*w0.w);
    m[4]=siluf(av1.x+bv1.x+d2*w1.x); m[5]=siluf(av1.y+bv1.y+d2*w1.y);
    m[6]=siluf(av1.z+bv1.z+d2*w1.z); m[7]=siluf(av1.w+bv1.w+d2*w1.w);
    split8(m, ah[kc], al[kc]);
  }

  // run boundaries for the scatter (shared by both column groups)
  const int rb = q*4;
  const int rd0 = dsts[wv][rb+0], rd1 = dsts[wv][rb+1];
  const int rd2 = dsts[wv][rb+2], rd3 = dsts[wv][rb+3];
  const bool b1 = (rd1!=rd0), b2 = (rd2!=rd1), b3 = (rd3!=rd2);

  float pd[4] = {0.f, 0.f, 0.f, 0.f};
  #pragma unroll
  for (int gi=0; gi<2; ++gi){
    f32x4 acc[4];
    #pragma unroll
    for (int tt=0;tt<4;tt++){ acc[tt][0]=0.f; acc[tt][1]=0.f; acc[tt][2]=0.f; acc[tt][3]=0.f; }
    #pragma unroll
    for (int kc=0;kc<4;kc++){
      #pragma unroll
      for (int tt=0;tt<4;tt++){
        const int col = (gi*4+tt)*16 + c;
        const short* fp = &w2t[kc*8192 + q*1024 + col*8];
        bf16x8 bh = *(const bf16x8*)fp;
        bf16x8 bl = *(const bf16x8*)(fp + 4096);
        acc[tt] = mma3(ah[kc], al[kc], bh, bl, acc[tt]);
      }
    }
    // epilogue for this column group: silu + pd partial + aggm scatter
    #pragma unroll
    for (int tt=0;tt<4;tt++){
      const int col = (gi*4+tt)*16 + c;
      const float be = be2s[col], wx = wxs[col];
      #pragma unroll
      for (int r=0;r<4;r++){
        float v = siluf(acc[tt][r] + be);
        acc[tt][r] = v;
        pd[r] += v*wx;
      }
      // static suffix-sum run compression
      float v3 = acc[tt][3];
      float v2 = acc[tt][2] + (b3 ? 0.f : v3);
      float v1 = acc[tt][1] + (b2 ? 0.f : v2);
      float v0 = acc[tt][0] + (b1 ? 0.f : v1);
      unsafeAtomicAdd(aggm + (size_t)rd0*128 + col, v0);
      if (b1) unsafeAtomicAdd(aggm + (size_t)rd1*128 + col, v1);
      if (b2) unsafeAtomicAdd(aggm + (size_t)rd2*128 + col, v2);
      if (b3) unsafeAtomicAdd(aggm + (size_t)rd3*128 + col, v3);
    }
  }
  #pragma unroll
  for (int msk=1; msk<16; msk<<=1){
    #pragma unroll
    for (int r=0;r<4;r++) pd[r] += __shfl_xor(pd[r], msk);
  }
  if (c < 3){ // agg_x scatter, component c
    float a0 = dxs[wv][rb+0][c]*tanh_fast(pd[0]);
    float a1 = dxs[wv][rb+1][c]*tanh_fast(pd[1]);
    float a2 = dxs[wv][rb+2][c]*tanh_fast(pd[2]);
    float a3 = dxs[wv][rb+3][c]*tanh_fast(pd[3]);
    float v3 = a3;
    float v2 = a2 + (b3 ? 0.f : v3);
    float v1 = a1 + (b2 ? 0.f : v2);
    float v0 = a0 + (b1 ? 0.f : v1);
    unsafeAtomicAdd(aggx + (size_t)rd0*3 + c, v0);
    if (b1) unsafeAtomicAdd(aggx + (size_t)rd1*3 + c, v1);
    if (b2) unsafeAtomicAdd(aggx + (size_t)rd2*3 + c, v2);
    if (b3) unsafeAtomicAdd(aggx + (size_t)rd3*3 + c, v3);
  }
}

// ---------------- masked mean pool (4-slice parallel) ----------------
__global__ __launch_bounds__(512) void k_pool(const float* __restrict__ h,
                                              const float* __restrict__ cvalid,
                                              float* __restrict__ pooled){
  __shared__ float red[4][128];
  __shared__ float redc[4];
  const int b = blockIdx.x, t = threadIdx.x, j = t&127, sl = t>>7;
  float s = 0.f, cf = 0.f;
  for (int n=sl; n<NPG; n+=4){
    const float m = cvalid[b*NPG + n];
    s  += h[((size_t)b*NPG + n)*DH + j] * m;
    cf += m;
  }
  red[sl][j] = s;
  if (j==0) redc[sl] = cf;
  __syncthreads();
  if (t < 128){
    float ss = red[0][t]+red[1][t]+red[2][t]+red[3][t];
    float cc = redc[0]+redc[1]+redc[2]+redc[3];
    pooled[b*DH + t] = ss / cc;
  }
}

// ---------------- final MLP head (single block) ----------------
__global__ __launch_bounds__(256) void k_mlp(const float* __restrict__ pooled,
                                             const float* __restrict__ Wfc,
                                             const float* __restrict__ bfc,
                                             const float* __restrict__ Wout,
                                             const float* __restrict__ bout,
                                             float* __restrict__ out)
{
  __shared__ __align__(16) float z[64*132];
  __shared__ __align__(16) float wB[128*128];
  const int t = threadIdx.x;
  {
    const int n = t>>2, qq = t&3;
    const float4* p = (const float4*)(pooled + n*DH + qq*32);
    float4* w = (float4*)&z[n*132 + qq*32];
    #pragma unroll
    for (int u=0;u<8;u++) w[u] = p[u];
  }
  const int g = t>>5, lane = t&31, c0 = lane*4;
  for (int l=0;l<3;l++){
    #pragma unroll
    for (int i=0;i<16;i++){
      const int idx = t + i*256;
      ((float4*)wB)[idx] = ((const float4*)(Wfc + (size_t)l*DH*DH))[idx];
    }
    __syncthreads();
    float acc[8][4];
    #pragma unroll
    for (int i=0;i<8;i++){ acc[i][0]=0.f; acc[i][1]=0.f; acc[i][2]=0.f; acc[i][3]=0.f; }
    #pragma unroll 4
    for (int kk=0; kk<128; kk+=4){
      float4 b0=*(const float4*)&wB[(kk+0)*128+c0];
      float4 b1=*(const float4*)&wB[(kk+1)*128+c0];
      float4 b2=*(const float4*)&wB[(kk+2)*128+c0];
      float4 b3=*(const float4*)&wB[(kk+3)*128+c0];
      #pragma unroll
      for (int i=0;i<8;i++){
        float4 a=*(const float4*)&z[(g*8+i)*132 + kk];
        acc[i][0]+=a.x*b0.x+a.y*b1.x+a.z*b2.x+a.w*b3.x;
        acc[i][1]+=a.x*b0.y+a.y*b1.y+a.z*b2.y+a.w*b3.y;
        acc[i][2]+=a.x*b0.z+a.y*b1.z+a.z*b2.z+a.w*b3.z;
        acc[i][3]+=a.x*b0.w+a.y*b1.w+a.z*b2.w+a.w*b3.w;
      }
    }
    __syncthreads();
    #pragma unroll
    for (int i=0;i<8;i++){
      float v0=acc[i][0]+bfc[l*DH+c0+0]; v0 = v0>0.f?v0:0.f;
      float v1=acc[i][1]+bfc[l*DH+c0+1]; v1 = v1>0.f?v1:0.f;
      float v2=acc[i][2]+bfc[l*DH+c0+2]; v2 = v2>0.f?v2:0.f;
      float v3=acc[i][3]+bfc[l*DH+c0+3]; v3 = v3>0.f?v3:0.f;
      float4 v; v.x=v0; v.y=v1; v.z=v2; v.w=v3;
      *(float4*)&z[(g*8+i)*132 + c0] = v;
    }
    __syncthreads();
  }
  if (t < 64){
    float a = 0.f;
    for (int k2=0;k2<128;k2++) a += z[t*132 + k2]*Wout[k2];
    out[t] = 1.0f/(1.0f + __expf(-(a + bout[0])));
  }
}

// ---------------- host ----------------
extern "C" void kernel_launch(void* const* d_in, const int* in_sizes, int n_in,
                              void* d_out, int out_size, void* d_ws, size_t ws_size,
                              hipStream_t stream)
{
  (void)in_sizes; (void)n_in; (void)out_size; (void)ws_size;
  const float* feat   = (const float*)d_in[0];
  const float* coords = (const float*)d_in[1];
  const float* cvalid = (const float*)d_in[2];
  const int*   esrc   = (const int*)d_in[3];
  const int*   edst   = (const int*)d_in[4];
  const int*   csrc   = (const int*)d_in[5];
  const int*   cdst   = (const int*)d_in[6];
  const float* W_emb  = (const float*)d_in[7];
  const float* We1    = (const float*)d_in[8];
  const float* be1    = (const float*)d_in[9];
  const float* We2    = (const float*)d_in[10];
  const float* be2    = (const float*)d_in[11];
  const float* Wx     = (const float*)d_in[12];
  const float* Wh     = (const float*)d_in[13];
  const float* bh     = (const float*)d_in[14];
  const float* Wfc    = (const float*)d_in[15];
  const float* bfc    = (const float*)d_in[16];
  const float* Wout   = (const float*)d_in[17];
  const float* bout   = (const float*)d_in[18];

  float* ws = (float*)d_ws;
  float* h      = ws; ws += (size_t)NT*DH;
  float* h0     = ws; ws += (size_t)NT*DH;
  float* c1     = ws; ws += (size_t)NT*DH;
  float* Aw     = ws; ws += (size_t)NT*DH;
  float* Bw     = ws; ws += (size_t)NT*DH;
  float* aggm   = ws; ws += (size_t)NT*DH;   // aggm & aggx adjacent -> single memset
  float* aggx   = ws; ws += (size_t)NT*3;
  float* x      = ws; ws += (size_t)NT*3;
  float* dgi    = ws; ws += NT;              // dgi & dci adjacent (scan2 indexes both)
  float* dci    = ws; ws += NT;
  float* pooled = ws; ws += BGR*DH;
  int2* sdG   = (int2*)ws; ws += (size_t)4*NE;  // 2*NE int2: graph pairs then cross pairs
  // cnt/cursor overlay c1 (sort phase finishes before c1 is first written)
  int* cnt    = (int*)c1;          // 2*NT
  int* cursor = cnt + 2*NT;        // 2*NT
  // split-plane packed weight arena (bf16 shorts)
  short* pst    = (short*)ws;
  short* wemb_p = pst;                       // K=128 -> 4 chunks -> 32768 shorts
  short* lay_p  = pst + 32768;

  // ---- zero accumulators once (consumers re-zero afterwards); aggm+aggx contiguous ----
  hipMemsetAsync(aggm, 0, (size_t)NT*(DH+3)*sizeof(float), stream);

  // ---- weight prep: single launch for all 16 matrices ----
  k_prep_all<<<1984, 256, 0, stream>>>(W_emb, We1, We2, Wh, wemb_p, lay_p);

  // ---- dst-sort both edge sets + degree inverses (4 launches total) ----
  hipMemsetAsync(cnt, 0, 2*NT*sizeof(int), stream);
  k_hist2   <<<2*(NE/256), 256, 0, stream>>>(edst, cdst, cnt);
  k_scan2   <<<2, 1024, 0, stream>>>(cnt, cursor, dgi);
  k_scatter2<<<2*(NE/256), 256, 0, stream>>>(esrc, edst, csrc, cdst, cursor, sdG);

  // ---- embedding: h = feat @ W_emb^T ; h0 = h ; x = coords ----
  k_ngemm<0><<<NT/64, 512, 0, stream>>>(feat, nullptr, nullptr, nullptr,
                                        wemb_p, nullptr, nullptr, nullptr, h, h0,
                                        nullptr, nullptr, nullptr);
  hipMemcpyAsync(x, coords, (size_t)NT*3*sizeof(float), hipMemcpyDeviceToDevice, stream);

  for (int k=0; k<LAYS; k++){
    short* p = lay_p + (size_t)k*LSTR;
    const float* We1_l = We1 + (size_t)k*257*DH;
    const float* be1_l = be1 + (size_t)k*DH;
    const float* be2_l = be2 + (size_t)k*DH;
    const float* Wx_l  = Wx  + (size_t)k*DH;
    const float* bh_l  = bh  + (size_t)k*DH;

    // node-side hoist of edge-MLP layer 1 (shared by graph & cross calls)
    k_ngemm<1><<<NT/64, 512, 0, stream>>>(h, nullptr, nullptr, nullptr,
                                          p, p + 32768, be1_l, nullptr, Aw, Bw,
                                          nullptr, nullptr, nullptr);
    // --- graph edges ---
    k_edge<<<NE/128, 512, 0, stream>>>(sdG, x, Aw, Bw,
                                       p + 65536, We1_l, be2_l, Wx_l, aggm, aggx);
    k_ngemm<2><<<NT/64, 512, 0, stream>>>(h, aggm, h0, dgi,
                                          p + 98304, nullptr, bh_l, nullptr, c1, nullptr,
                                          x, coords, aggx);
    // --- cross edges ---
    k_edge<<<NE/128, 512, 0, stream>>>(sdG + NE, x, Aw, Bw,
                                       p + 65536, We1_l, be2_l, Wx_l, aggm, aggx);
    k_ngemm<3><<<NT/64, 512, 0, stream>>>(h, aggm, h0, dci,
                                          p + 98304, nullptr, bh_l, c1, h, nullptr,
                                          x, coords, aggx);
  }

  k_pool<<<BGR, 512, 0, stream>>>(h, cvalid, pooled);
  k_mlp <<<1, 256, 0, stream>>>(pooled, Wfc, bfc, Wout, bout, (float*)d_out);
}

// Round 10
// 1673.997 us; speedup vs baseline: 1.1988x; 1.0115x over previous
//
#include <hip/hip_runtime.h>

#define DEVINL __device__ __forceinline__

constexpr int NT   = 32768;   // 64*512 nodes
constexpr int DH   = 128;
constexpr int NE   = 262144;
constexpr int BGR  = 64;
constexpr int NPG  = 512;
constexpr int LAYS = 5;
constexpr size_t LSTR = 32768*3 + 98304;   // per-layer packed: we1a, we1b, we2, wh

typedef __attribute__((ext_vector_type(8))) short bf16x8;
typedef __attribute__((ext_vector_type(4))) float f32x4;
typedef __attribute__((ext_vector_type(4))) unsigned int uint4v;
typedef unsigned int uint;

DEVINL float siluf(float v){ return v * (1.0f/(1.0f + __expf(-v))); }
DEVINL float tanh_fast(float x){ float e = __expf(2.0f*x); return 1.0f - 2.0f/(e + 1.0f); }

DEVINL uint bf16_rne(float f){
  uint x = __float_as_uint(f);
  return (x + 0x7fffu + ((x>>16)&1u)) >> 16;
}

// split one f32 into hi (truncated bf16) + lo (rne bf16 of residual): ~16-bit mantissa total
DEVINL void split8(const float* m, bf16x8& h, bf16x8& l){
  #pragma unroll
  for (int j=0;j<8;j++){
    uint x  = __float_as_uint(m[j]);
    uint hb = x >> 16;
    float hf = __uint_as_float(hb<<16);
    uint lb = bf16_rne(m[j] - hf);
    h[j] = (short)hb; l[j] = (short)lb;
  }
}

// 3-term split-bf16 MFMA accumulate: acc += A*B with ~f32 precision (drops al*bl)
DEVINL f32x4 mma3(bf16x8 ah, bf16x8 al, bf16x8 bh, bf16x8 bl, f32x4 acc){
  acc = __builtin_amdgcn_mfma_f32_16x16x32_bf16(al, bh, acc, 0,0,0);
  acc = __builtin_amdgcn_mfma_f32_16x16x32_bf16(ah, bl, acc, 0,0,0);
  acc = __builtin_amdgcn_mfma_f32_16x16x32_bf16(ah, bh, acc, 0,0,0);
  return acc;
}

#define GLOAD_LDS16(g, l) __builtin_amdgcn_global_load_lds( \
    (const __attribute__((address_space(1))) void*)(g), \
    (__attribute__((address_space(3))) void*)(l), 16, 0, 0)

// ---------------- fused weight prep: all 16 weight matrices in ONE launch ----------------
__global__ __launch_bounds__(256) void k_prep_all(
    const float* __restrict__ W_emb, const float* __restrict__ We1,
    const float* __restrict__ We2,  const float* __restrict__ Wh,
    short* __restrict__ wemb_p, short* __restrict__ lay_p)
{
  const int idx = blockIdx.x*256 + threadIdx.x;
  const float* src; short* dst; int v; bool trans = false;
  if (idx < 16384){ src = W_emb; dst = wemb_p; v = idx; trans = true; }
  else {
    const int u = idx - 16384;
    const int layer = u / 98304;
    const int w = u - layer*98304;
    short* p = lay_p + (size_t)layer*LSTR;
    if (w < 16384)      { src = We1 + (size_t)layer*257*DH;          dst = p;         v = w; }
    else if (w < 32768) { src = We1 + (size_t)layer*257*DH + 128*DH; dst = p + 32768; v = w - 16384; }
    else if (w < 49152) { src = We2 + (size_t)layer*DH*DH;           dst = p + 65536; v = w - 32768; }
    else                { src = Wh  + (size_t)layer*3*DH*DH;         dst = p + 98304; v = w - 49152; }
  }
  const int k = v>>7, col = v&127;
  const float val = trans ? src[(size_t)col*128 + k] : src[(size_t)k*128 + col];
  uint hb = __float_as_uint(val) >> 16;
  float hf = __uint_as_float(hb<<16);
  uint lb = bf16_rne(val - hf);
  const int kc = k>>5, q = (k&31)>>3, j = k&7;
  const size_t o = (size_t)kc*8192 + q*1024 + col*8 + j;
  dst[o]        = (short)hb;
  dst[o + 4096] = (short)lb;
}

// ---------------- sort / degree (both edge sets per launch) ----------------
__global__ __launch_bounds__(256) void k_hist2(const int* __restrict__ edst,
                                               const int* __restrict__ cdst,
                                               int* __restrict__ cnt){
  const int half = blockIdx.x >= (NE/256);
  const int e = (blockIdx.x - half*(NE/256))*256 + threadIdx.x;
  const int* d = half ? cdst : edst;
  atomicAdd(&cnt[half*NT + d[e]], 1);
}

__global__ __launch_bounds__(1024) void k_scan2(const int* __restrict__ cnt,
                                                int* __restrict__ cur,
                                                float* __restrict__ dinv){
  __shared__ int part[1024];
  const int off = blockIdx.x * NT;
  const int tid = threadIdx.x;
  const int base = tid*32;
  int s = 0;
  for (int i=0;i<32;i++){
    const int c = cnt[off + base + i];
    dinv[off + base + i] = 1.0f / (float)(c > 1 ? c : 1);
    s += c;
  }
  const int own = s;
  part[tid] = s; __syncthreads();
  for (int o=1; o<1024; o<<=1){
    int v = (tid>=o) ? part[tid-o] : 0;
    __syncthreads();
    part[tid] += v;
    __syncthreads();
  }
  int run = part[tid] - own;
  for (int i=0;i<32;i++){ cur[off + base + i] = run; run += cnt[off + base + i]; }
}

// writes dst-sorted (src,dst) pairs -> k_edge needs ONE load to get both ids
__global__ __launch_bounds__(256) void k_scatter2(const int* __restrict__ esrc,
                                                  const int* __restrict__ edst,
                                                  const int* __restrict__ csrc,
                                                  const int* __restrict__ cdst,
                                                  int* __restrict__ cur,
                                                  int2* __restrict__ sd){
  const int half = blockIdx.x >= (NE/256);
  const int e = (blockIdx.x - half*(NE/256))*256 + threadIdx.x;
  const int* sA = half ? csrc : esrc;
  const int* dA = half ? cdst : edst;
  const int dv = dA[e];
  const int p = atomicAdd(&cur[half*NT + dv], 1);
  int2 v; v.x = sA[e]; v.y = dv;
  sd[half*NE + p] = v;
}

// ---------------- node-side MFMA GEMM: 64 rows/block, 512 blocks, 8 waves, NO LDS/barriers ----
// Wave layout R10: 2 row-tile-pairs x 4 col-groups. Each wave owns 32 rows (2 MFMA row
// tiles) x 2 col-tiles (cols cgrp & cgrp+4) -> weight-fragment duplication per block 4x->2x
// (same MFMA count, same A traffic). Weights read from L2-resident packed planes.
// MODE 0: embed  (A=feat, K=128, out h & h0)
// MODE 1: proj2  (A=h, K=128, mat0 -> Aw=h@We1a+be1, mat1 -> Bw=h@We1b)
// MODE 2: hupd1  (A=[h|aggm*dinv|h0], K=384, out c1; fused x-update+aggx-zero; zeroes aggm)
// MODE 3: hupd2  (same, out h = silu(.+bh) - c1; fused x-update; zeroes aggm)
template<int MODE>
__global__ __launch_bounds__(512) void k_ngemm(
    const float* __restrict__ A0, float* __restrict__ A1, const float* __restrict__ A2,
    const float* __restrict__ dinv, const short* __restrict__ W0, const short* __restrict__ W1,
    const float* __restrict__ bias, const float* __restrict__ c1in,
    float* __restrict__ out0, float* __restrict__ out1,
    float* __restrict__ xv, const float* __restrict__ x0, float* __restrict__ aggx)
{
  const int tid = threadIdx.x;
  const int wv = tid>>6, lane = tid&63, c = lane&15, q = lane>>4;
  const int rowt = wv & 1, cgrp = wv >> 1;
  const int base = blockIdx.x*64 + rowt*32;
  const int row0 = base + c, row1 = base + 16 + c;
  constexpr int KC = (MODE>=2) ? 12 : 4;
  if constexpr (MODE>=2){
    // fused coordinate update for this block's 64 exclusive nodes (replaces k_xupd)
    if (tid < 192){
      const int i = blockIdx.x*192 + tid;
      const int nn = i/3;
      xv[i] = 0.25f*x0[i] + 0.75f*xv[i] + aggx[i]*dinv[nn];
      aggx[i] = 0.f;
    }
  }
  float dv0 = 1.0f, dv1 = 1.0f;
  if constexpr (MODE>=2){ dv0 = dinv[row0]; dv1 = dinv[row1]; }

  constexpr int NA = (MODE==1) ? 8 : 4;   // MODE1: [rt*4 + mat*2 + tt]; else [rt*2 + tt]
  f32x4 acc[NA];
  #pragma unroll
  for (int t=0;t<NA;t++){ acc[t][0]=0.f; acc[t][1]=0.f; acc[t][2]=0.f; acc[t][3]=0.f; }

  #pragma unroll
  for (int kc=0; kc<KC; ++kc){
    const float* asrc = A0; float s0 = 1.0f, s1 = 1.0f;
    if constexpr (MODE>=2){
      if (kc >= 8)      { asrc = A2; }
      else if (kc >= 4) { asrc = A1; s0 = dv0; s1 = dv1; }
    }
    const int koff = (kc&3)*32 + q*8;
    float4 u0 = *(const float4*)(asrc + (size_t)row0*128 + koff);
    float4 u1 = *(const float4*)(asrc + (size_t)row0*128 + koff + 4);
    float4 w0 = *(const float4*)(asrc + (size_t)row1*128 + koff);
    float4 w1 = *(const float4*)(asrc + (size_t)row1*128 + koff + 4);
    float m0[8] = {u0.x*s0,u0.y*s0,u0.z*s0,u0.w*s0,u1.x*s0,u1.y*s0,u1.z*s0,u1.w*s0};
    float m1[8] = {w0.x*s1,w0.y*s1,w0.z*s1,w0.w*s1,w1.x*s1,w1.y*s1,w1.z*s1,w1.w*s1};
    bf16x8 ah0, al0, ah1, al1;
    split8(m0, ah0, al0);
    split8(m1, ah1, al1);
    if constexpr (MODE==1){
      #pragma unroll
      for (int mat=0; mat<2; ++mat){
        const short* Wp = mat ? W1 : W0;
        #pragma unroll
        for (int tt=0; tt<2; ++tt){
          const int t = cgrp + tt*4;
          const short* fp = Wp + (size_t)kc*8192 + q*1024 + (t*16 + c)*8;
          bf16x8 bh = *(const bf16x8*)fp;
          bf16x8 bl = *(const bf16x8*)(fp + 4096);
          acc[0 + mat*2 + tt] = mma3(ah0, al0, bh, bl, acc[0 + mat*2 + tt]);
          acc[4 + mat*2 + tt] = mma3(ah1, al1, bh, bl, acc[4 + mat*2 + tt]);
        }
      }
    } else {
      #pragma unroll
      for (int tt=0; tt<2; ++tt){
        const int t = cgrp + tt*4;
        const short* fp = W0 + (size_t)kc*8192 + q*1024 + (t*16 + c)*8;
        bf16x8 bh = *(const bf16x8*)fp;
        bf16x8 bl = *(const bf16x8*)(fp + 4096);
        acc[tt]     = mma3(ah0, al0, bh, bl, acc[tt]);
        acc[2 + tt] = mma3(ah1, al1, bh, bl, acc[2 + tt]);
      }
    }
  }
  // epilogue: C row = base + rt*16 + q*4 + r, col = (cgrp + tt*4)*16 + c
  if constexpr (MODE==1){
    #pragma unroll
    for (int rt=0; rt<2; ++rt){
      #pragma unroll
      for (int tt=0; tt<2; ++tt){
        const int col = (cgrp + tt*4)*16 + c;
        const float b0 = bias[col];
        #pragma unroll
        for (int r=0;r<4;r++){
          const size_t orow = (size_t)base + rt*16 + q*4 + r;
          out0[orow*128 + col] = acc[rt*4 + 0 + tt][r] + b0;   // Aw (be1 folded)
          out1[orow*128 + col] = acc[rt*4 + 2 + tt][r];        // Bw
        }
      }
    }
  } else {
    #pragma unroll
    for (int rt=0; rt<2; ++rt){
      #pragma unroll
      for (int tt=0; tt<2; ++tt){
        const int col = (cgrp + tt*4)*16 + c;
        float b0 = 0.f;
        if constexpr (MODE>=2) b0 = bias[col];
        #pragma unroll
        for (int r=0;r<4;r++){
          const size_t orow = (size_t)base + rt*16 + q*4 + r;
          float v = acc[rt*2 + tt][r];
          if constexpr (MODE==0){
            out0[orow*128 + col] = v; out1[orow*128 + col] = v;
          } else if constexpr (MODE==2){
            out0[orow*128 + col] = siluf(v + b0);
          } else {
            out0[orow*128 + col] = siluf(v + b0) - c1in[orow*128 + col];
          }
        }
      }
    }
  }
  if constexpr (MODE>=2){
    // consume-and-zero this block's aggm rows (block-exclusive; all reads done above)
    __syncthreads();
    float4 z; z.x=0.f; z.y=0.f; z.z=0.f; z.w=0.f;
    float4* zp = (float4*)(A1 + (size_t)blockIdx.x*64*128);
    #pragma unroll
    for (int i=0;i<4;i++) zp[tid + i*512] = z;
  }
}

// ---------------- fused edge MLP (MFMA) + scatter: 128 dst-sorted edges per block ----------------
// FROZEN R7 champion (105 us). R8 lesson: raising occupancy (4 blocks/CU) widens the resident
// dst-window -> active aggm lines exceed per-XCD L2 -> atomic write-backs to HBM (WRITE 60->261MB)
// AND tight VGPR bounds spill. 2 blocks/CU + single barrier + pre-issued gathers is the optimum
// found for this structure; do NOT chase occupancy here.
__global__ __launch_bounds__(512, 4) void k_edge(
    const int2* __restrict__ sd, const float* __restrict__ x,
    const float* __restrict__ Aw, const float* __restrict__ Bw,
    const short* __restrict__ w2p, const float* __restrict__ We1_l,
    const float* __restrict__ be2_l, const float* __restrict__ Wx_l,
    float* __restrict__ aggm, float* __restrict__ aggx)
{
  __shared__ __align__(16) short w2t[32768];   // 64 KB: full We2 (4 chunks x hi/lo)
  __shared__ __align__(16) float w256s[128];
  __shared__ __align__(16) float wxs[128];
  __shared__ __align__(16) float be2s[128];
  __shared__ float dxs[8][16][3];              // per-wave scratch (intra-wave only)
  __shared__ int   dsts[8][16];
  const int tid = threadIdx.x;
  const int wv = tid>>6, lane = tid&63, c = lane&15, q = lane>>4;
  const int er = wv*16 + c;
  // (1) edge pair: single coalesced load, oldest in the vmem queue
  const int2 sdv = sd[blockIdx.x*128 + er];
  // (2) async-stage full We2 directly into LDS (wave-uniform base + lane*16 pattern)
  #pragma unroll
  for (int i=0;i<8;i++)
    GLOAD_LDS16(w2p + (size_t)(tid + i*512)*8, w2t + (size_t)(wv*64 + i*512)*8);
  if (tid < 128){ w256s[tid]=We1_l[256*128+tid]; wxs[tid]=Wx_l[tid]; be2s[tid]=be2_l[tid]; }
  const int s = sdv.x, d = sdv.y;
  // (3) issue ALL gathers now; they land by the barrier
  const float xs0=x[s*3+0], xs1=x[s*3+1], xs2=x[s*3+2];
  const float xd0=x[d*3+0], xd1=x[d*3+1], xd2=x[d*3+2];
  const float* ap = Aw + (size_t)s*128 + q*8;
  const float* bp = Bw + (size_t)d*128 + q*8;
  float4 aa[8], bb[8];
  #pragma unroll
  for (int kc=0;kc<4;kc++){
    aa[2*kc]   = *(const float4*)(ap + kc*32);
    aa[2*kc+1] = *(const float4*)(ap + kc*32 + 4);
    bb[2*kc]   = *(const float4*)(bp + kc*32);
    bb[2*kc+1] = *(const float4*)(bp + kc*32 + 4);
  }
  const float dx0 = xs0-xd0, dx1 = xs1-xd1, dx2 = xs2-xd2;
  const float d2  = dx0*dx0 + dx1*dx1 + dx2*dx2;
  if (q==0){ dxs[wv][c][0]=dx0; dxs[wv][c][1]=dx1; dxs[wv][c][2]=dx2; dsts[wv][c]=d; }
  __syncthreads();   // the ONLY barrier: drains staging + gathers

  // m1 fragments for all 4 k-chunks (pure VALU now)
  bf16x8 ah[4], al[4];
  #pragma unroll
  for (int kc=0;kc<4;kc++){
    const int kb = kc*32 + q*8;
    float4 w0 = *(const float4*)&w256s[kb], w1 = *(const float4*)&w256s[kb+4];
    float4 av0=aa[2*kc], av1=aa[2*kc+1], bv0=bb[2*kc], bv1=bb[2*kc+1];
    float m[8];
    m[0]=siluf(av0.x+bv0.x+d2*w0.x); m[1]=siluf(av0.y+bv0.y+d2*w0.y);
    m[2]=siluf(av0.z+bv0.z+d2*w0.z); m[3]=siluf(av0.w+bv0.w+d2*w0.w);
    m[4]=siluf(av1.x+bv1.x+d2*w1.x); m[5]=siluf(av1.y+bv1.y+d2*w1.y);
    m[6]=siluf(av1.z+bv1.z+d2*w1.z); m[7]=siluf(av1.w+bv1.w+d2*w1.w);
    split8(m, ah[kc], al[kc]);
  }

  // run boundaries for the scatter (shared by both column groups)
  const int rb = q*4;
  const int rd0 = dsts[wv][rb+0], rd1 = dsts[wv][rb+1];
  const int rd2 = dsts[wv][rb+2], rd3 = dsts[wv][rb+3];
  const bool b1 = (rd1!=rd0), b2 = (rd2!=rd1), b3 = (rd3!=rd2);

  float pd[4] = {0.f, 0.f, 0.f, 0.f};
  #pragma unroll
  for (int gi=0; gi<2; ++gi){
    f32x4 acc[4];
    #pragma unroll
    for (int tt=0;tt<4;tt++){ acc[tt][0]=0.f; acc[tt][1]=0.f; acc[tt][2]=0.f; acc[tt][3]=0.f; }
    #pragma unroll
    for (int kc=0;kc<4;kc++){
      #pragma unroll
      for (int tt=0;tt<4;tt++){
        const int col = (gi*4+tt)*16 + c;
        const short* fp = &w2t[kc*8192 + q*1024 + col*8];
        bf16x8 bh = *(const bf16x8*)fp;
        bf16x8 bl = *(const bf16x8*)(fp + 4096);
        acc[tt] = mma3(ah[kc], al[kc], bh, bl, acc[tt]);
      }
    }
    // epilogue for this column group: silu + pd partial + aggm scatter
    #pragma unroll
    for (int tt=0;tt<4;tt++){
      const int col = (gi*4+tt)*16 + c;
      const float be = be2s[col], wx = wxs[col];
      #pragma unroll
      for (int r=0;r<4;r++){
        float v = siluf(acc[tt][r] + be);
        acc[tt][r] = v;
        pd[r] += v*wx;
      }
      // static suffix-sum run compression
      float v3 = acc[tt][3];
      float v2 = acc[tt][2] + (b3 ? 0.f : v3);
      float v1 = acc[tt][1] + (b2 ? 0.f : v2);
      float v0 = acc[tt][0] + (b1 ? 0.f : v1);
      unsafeAtomicAdd(aggm + (size_t)rd0*128 + col, v0);
      if (b1) unsafeAtomicAdd(aggm + (size_t)rd1*128 + col, v1);
      if (b2) unsafeAtomicAdd(aggm + (size_t)rd2*128 + col, v2);
      if (b3) unsafeAtomicAdd(aggm + (size_t)rd3*128 + col, v3);
    }
  }
  #pragma unroll
  for (int msk=1; msk<16; msk<<=1){
    #pragma unroll
    for (int r=0;r<4;r++) pd[r] += __shfl_xor(pd[r], msk);
  }
  if (c < 3){ // agg_x scatter, component c
    float a0 = dxs[wv][rb+0][c]*tanh_fast(pd[0]);
    float a1 = dxs[wv][rb+1][c]*tanh_fast(pd[1]);
    float a2 = dxs[wv][rb+2][c]*tanh_fast(pd[2]);
    float a3 = dxs[wv][rb+3][c]*tanh_fast(pd[3]);
    float v3 = a3;
    float v2 = a2 + (b3 ? 0.f : v3);
    float v1 = a1 + (b2 ? 0.f : v2);
    float v0 = a0 + (b1 ? 0.f : v1);
    unsafeAtomicAdd(aggx + (size_t)rd0*3 + c, v0);
    if (b1) unsafeAtomicAdd(aggx + (size_t)rd1*3 + c, v1);
    if (b2) unsafeAtomicAdd(aggx + (size_t)rd2*3 + c, v2);
    if (b3) unsafeAtomicAdd(aggx + (size_t)rd3*3 + c, v3);
  }
}

// ---------------- masked mean pool (4-slice parallel) ----------------
__global__ __launch_bounds__(512) void k_pool(const float* __restrict__ h,
                                              const float* __restrict__ cvalid,
                                              float* __restrict__ pooled){
  __shared__ float red[4][128];
  __shared__ float redc[4];
  const int b = blockIdx.x, t = threadIdx.x, j = t&127, sl = t>>7;
  float s = 0.f, cf = 0.f;
  for (int n=sl; n<NPG; n+=4){
    const float m = cvalid[b*NPG + n];
    s  += h[((size_t)b*NPG + n)*DH + j] * m;
    cf += m;
  }
  red[sl][j] = s;
  if (j==0) redc[sl] = cf;
  __syncthreads();
  if (t < 128){
    float ss = red[0][t]+red[1][t]+red[2][t]+red[3][t];
    float cc = redc[0]+redc[1]+redc[2]+redc[3];
    pooled[b*DH + t] = ss / cc;
  }
}

// ---------------- final MLP head (single block) ----------------
__global__ __launch_bounds__(256) void k_mlp(const float* __restrict__ pooled,
                                             const float* __restrict__ Wfc,
                                             const float* __restrict__ bfc,
                                             const float* __restrict__ Wout,
                                             const float* __restrict__ bout,
                                             float* __restrict__ out)
{
  __shared__ __align__(16) float z[64*132];
  __shared__ __align__(16) float wB[128*128];
  const int t = threadIdx.x;
  {
    const int n = t>>2, qq = t&3;
    const float4* p = (const float4*)(pooled + n*DH + qq*32);
    float4* w = (float4*)&z[n*132 + qq*32];
    #pragma unroll
    for (int u=0;u<8;u++) w[u] = p[u];
  }
  const int g = t>>5, lane = t&31, c0 = lane*4;
  for (int l=0;l<3;l++){
    #pragma unroll
    for (int i=0;i<16;i++){
      const int idx = t + i*256;
      ((float4*)wB)[idx] = ((const float4*)(Wfc + (size_t)l*DH*DH))[idx];
    }
    __syncthreads();
    float acc[8][4];
    #pragma unroll
    for (int i=0;i<8;i++){ acc[i][0]=0.f; acc[i][1]=0.f; acc[i][2]=0.f; acc[i][3]=0.f; }
    #pragma unroll 4
    for (int kk=0; kk<128; kk+=4){
      float4 b0=*(const float4*)&wB[(kk+0)*128+c0];
      float4 b1=*(const float4*)&wB[(kk+1)*128+c0];
      float4 b2=*(const float4*)&wB[(kk+2)*128+c0];
      float4 b3=*(const float4*)&wB[(kk+3)*128+c0];
      #pragma unroll
      for (int i=0;i<8;i++){
        float4 a=*(const float4*)&z[(g*8+i)*132 + kk];
        acc[i][0]+=a.x*b0.x+a.y*b1.x+a.z*b2.x+a.w*b3.x;
        acc[i][1]+=a.x*b0.y+a.y*b1.y+a.z*b2.y+a.w*b3.y;
        acc[i][2]+=a.x*b0.z+a.y*b1.z+a.z*b2.z+a.w*b3.z;
        acc[i][3]+=a.x*b0.w+a.y*b1.w+a.z*b2.w+a.w*b3.w;
      }
    }
    __syncthreads();
    #pragma unroll
    for (int i=0;i<8;i++){
      float v0=acc[i][0]+bfc[l*DH+c0+0]; v0 = v0>0.f?v0:0.f;
      float v1=acc[i][1]+bfc[l*DH+c0+1]; v1 = v1>0.f?v1:0.f;
      float v2=acc[i][2]+bfc[l*DH+c0+2]; v2 = v2>0.f?v2:0.f;
      float v3=acc[i][3]+bfc[l*DH+c0+3]; v3 = v3>0.f?v3:0.f;
      float4 v; v.x=v0; v.y=v1; v.z=v2; v.w=v3;
      *(float4*)&z[(g*8+i)*132 + c0] = v;
    }
    __syncthreads();
  }
  if (t < 64){
    float a = 0.f;
    for (int k2=0;k2<128;k2++) a += z[t*132 + k2]*Wout[k2];
    out[t] = 1.0f/(1.0f + __expf(-(a + bout[0])));
  }
}

// ---------------- host ----------------
extern "C" void kernel_launch(void* const* d_in, const int* in_sizes, int n_in,
                              void* d_out, int out_size, void* d_ws, size_t ws_size,
                              hipStream_t stream)
{
  (void)in_sizes; (void)n_in; (void)out_size; (void)ws_size;
  const float* feat   = (const float*)d_in[0];
  const float* coords = (const float*)d_in[1];
  const float* cvalid = (const float*)d_in[2];
  const int*   esrc   = (const int*)d_in[3];
  const int*   edst   = (const int*)d_in[4];
  const int*   csrc   = (const int*)d_in[5];
  const int*   cdst   = (const int*)d_in[6];
  const float* W_emb  = (const float*)d_in[7];
  const float* We1    = (const float*)d_in[8];
  const float* be1    = (const float*)d_in[9];
  const float* We2    = (const float*)d_in[10];
  const float* be2    = (const float*)d_in[11];
  const float* Wx     = (const float*)d_in[12];
  const float* Wh     = (const float*)d_in[13];
  const float* bh     = (const float*)d_in[14];
  const float* Wfc    = (const float*)d_in[15];
  const float* bfc    = (const float*)d_in[16];
  const float* Wout   = (const float*)d_in[17];
  const float* bout   = (const float*)d_in[18];

  float* ws = (float*)d_ws;
  float* h      = ws; ws += (size_t)NT*DH;
  float* h0     = ws; ws += (size_t)NT*DH;
  float* c1     = ws; ws += (size_t)NT*DH;
  float* Aw     = ws; ws += (size_t)NT*DH;
  float* Bw     = ws; ws += (size_t)NT*DH;
  float* aggm   = ws; ws += (size_t)NT*DH;   // aggm & aggx adjacent -> single memset
  float* aggx   = ws; ws += (size_t)NT*3;
  float* x      = ws; ws += (size_t)NT*3;
  float* dgi    = ws; ws += NT;              // dgi & dci adjacent (scan2 indexes both)
  float* dci    = ws; ws += NT;
  float* pooled = ws; ws += BGR*DH;
  int2* sdG   = (int2*)ws; ws += (size_t)4*NE;  // 2*NE int2: graph pairs then cross pairs
  // cnt/cursor overlay c1 (sort phase finishes before c1 is first written)
  int* cnt    = (int*)c1;          // 2*NT
  int* cursor = cnt + 2*NT;        // 2*NT
  // split-plane packed weight arena (bf16 shorts)
  short* pst    = (short*)ws;
  short* wemb_p = pst;                       // K=128 -> 4 chunks -> 32768 shorts
  short* lay_p  = pst + 32768;

  // ---- zero accumulators once (consumers re-zero afterwards); aggm+aggx contiguous ----
  hipMemsetAsync(aggm, 0, (size_t)NT*(DH+3)*sizeof(float), stream);

  // ---- weight prep: single launch for all 16 matrices ----
  k_prep_all<<<1984, 256, 0, stream>>>(W_emb, We1, We2, Wh, wemb_p, lay_p);

  // ---- dst-sort both edge sets + degree inverses (4 launches total) ----
  hipMemsetAsync(cnt, 0, 2*NT*sizeof(int), stream);
  k_hist2   <<<2*(NE/256), 256, 0, stream>>>(edst, cdst, cnt);
  k_scan2   <<<2, 1024, 0, stream>>>(cnt, cursor, dgi);
  k_scatter2<<<2*(NE/256), 256, 0, stream>>>(esrc, edst, csrc, cdst, cursor, sdG);

  // ---- embedding: h = feat @ W_emb^T ; h0 = h ; x = coords ----
  k_ngemm<0><<<NT/64, 512, 0, stream>>>(feat, nullptr, nullptr, nullptr,
                                        wemb_p, nullptr, nullptr, nullptr, h, h0,
                                        nullptr, nullptr, nullptr);
  hipMemcpyAsync(x, coords, (size_t)NT*3*sizeof(float), hipMemcpyDeviceToDevice, stream);

  for (int k=0; k<LAYS; k++){
    short* p = lay_p + (size_t)k*LSTR;
    const float* We1_l = We1 + (size_t)k*257*DH;
    const float* be1_l = be1 + (size_t)k*DH;
    const float* be2_l = be2 + (size_t)k*DH;
    const float* Wx_l  = Wx  + (size_t)k*DH;
    const float* bh_l  = bh  + (size_t)k*DH;

    // node-side hoist of edge-MLP layer 1 (shared by graph & cross calls)
    k_ngemm<1><<<NT/64, 512, 0, stream>>>(h, nullptr, nullptr, nullptr,
                                          p, p + 32768, be1_l, nullptr, Aw, Bw,
                                          nullptr, nullptr, nullptr);
    // --- graph edges ---
    k_edge<<<NE/128, 512, 0, stream>>>(sdG, x, Aw, Bw,
                                       p + 65536, We1_l, be2_l, Wx_l, aggm, aggx);
    k_ngemm<2><<<NT/64, 512, 0, stream>>>(h, aggm, h0, dgi,
                                          p + 98304, nullptr, bh_l, nullptr, c1, nullptr,
                                          x, coords, aggx);
    // --- cross edges ---
    k_edge<<<NE/128, 512, 0, stream>>>(sdG + NE, x, Aw, Bw,
                                       p + 65536, We1_l, be2_l, Wx_l, aggm, aggx);
    k_ngemm<3><<<NT/64, 512, 0, stream>>>(h, aggm, h0, dci,
                                          p + 98304, nullptr, bh_l, c1, h, nullptr,
                                          x, coords, aggx);
  }

  k_pool<<<BGR, 512, 0, stream>>>(h, cvalid, pooled);
  k_mlp <<<1, 256, 0, stream>>>(pooled, Wfc, bfc, Wout, bout, (float*)d_out);
}